// Round 5
// baseline (23.491 us; speedup 1.0000x reference)
//
#include <hip/hip_runtime.h>

#define D0 128
#define D1 128
#define D2 96
#define TW 8                 // owned tile width in x and y
#define EXT 12               // TW + 2*2 halo (dil needs bnd+-1, bnd needs occ+-2)
#define BND 10               // EXT - 2 (region where boundary words are valid)
#define NBX (D0 / TW)        // 16
#define NBY (D1 / TW)        // 16
#define NBLKS (NBX * NBY)    // 256 blocks / partials
#define FLAG_SET 0x13579BDFu
#define FLAG_STRIDE 16       // 16 u32 = 64 B: one cache line per flag

// ---------------------------------------------------------------------------
// Single fused kernel: pack -> boundary -> 7-point dilation (d2<=1) -> counts
// -> flag handshake -> block (0,0) reduces all partials and writes the scalar.
// No atomic RMW anywhere; flags are padded release-stores on distinct lines.
// ---------------------------------------------------------------------------
__global__ __launch_bounds__(512) void fused_kernel(const float* __restrict__ net,
                                                    const int* __restrict__ tgt,
                                                    uint4* __restrict__ partials,
                                                    unsigned int* __restrict__ flags,
                                                    float* __restrict__ out) {
    __shared__ unsigned int pk[2][EXT][EXT][3];   // packed occupancy (p,g)
    __shared__ unsigned int bd[2][BND][BND][3];   // boundary words (p,g)
    __shared__ unsigned long long wsum[8];
    __shared__ unsigned int s[4][256];            // final reduce (block 0 only)

    const int tid  = threadIdx.x;
    const int lane = tid & 63;
    const int wid  = tid >> 6;                    // 8 waves
    const int x0   = blockIdx.x * TW;
    const int y0   = blockIdx.y * TW;

    // ---- Phase A: pack 12x12 ext columns (96 z -> 3 words) via ballot.
    // Wave w owns ext-columns [w*18, w*18+18); batch 6 columns so 24 global
    // loads are in flight per wave before the first ballot consumes them.
    for (int c0 = wid * 18; c0 < wid * 18 + 18; c0 += 6) {
        bool pl[6], gl[6], ph[6], gh[6];
        #pragma unroll
        for (int j = 0; j < 6; ++j) {
            int c  = c0 + j;
            int ex = c / EXT, ey = c % EXT;
            int cx = x0 - 2 + ex, cy = y0 - 2 + ey;
            bool in = (cx >= 0 && cx < D0 && cy >= 0 && cy < D1);
            long base = in ? ((long)(cx * D1 + cy)) * D2 : 0;
            bool in2 = in && (lane < 32);
            pl[j] = in  ? (net[base + lane] > 0.0f)      : false;  // z in [0,64)
            gl[j] = in  ? (tgt[base + lane] != 0)        : false;
            ph[j] = in2 ? (net[base + 64 + lane] > 0.0f) : false;  // z in [64,96)
            gh[j] = in2 ? (tgt[base + 64 + lane] != 0)   : false;
        }
        #pragma unroll
        for (int j = 0; j < 6; ++j) {
            unsigned long long mp  = __ballot(pl[j]);
            unsigned long long mg  = __ballot(gl[j]);
            unsigned long long mp2 = __ballot(ph[j]);
            unsigned long long mg2 = __ballot(gh[j]);
            if (lane == 0) {
                int c  = c0 + j;
                int ex = c / EXT, ey = c % EXT;
                pk[0][ex][ey][0] = (unsigned int)mp;
                pk[0][ex][ey][1] = (unsigned int)(mp >> 32);
                pk[0][ex][ey][2] = (unsigned int)mp2;
                pk[1][ex][ey][0] = (unsigned int)mg;
                pk[1][ex][ey][1] = (unsigned int)(mg >> 32);
                pk[1][ex][ey][2] = (unsigned int)mg2;
            }
        }
    }
    __syncthreads();

    // ---- Phase B: boundary words on the 10x10 ext-1 region (both grids).
    for (int it = tid; it < 2 * BND * BND * 3; it += 512) {
        int gr = it / (BND * BND * 3);
        int r  = it % (BND * BND * 3);
        int bx = r / (BND * 3);
        int r2 = r % (BND * 3);
        int by = r2 / 3;
        int wz = r2 % 3;
        int ex = bx + 1, ey = by + 1;
        unsigned int w = pk[gr][ex][ey][wz];
        unsigned int bres = 0u;
        if (w) {
            unsigned int nxm = pk[gr][ex - 1][ey][wz];
            unsigned int nxp = pk[gr][ex + 1][ey][wz];
            unsigned int nym = pk[gr][ex][ey - 1][wz];
            unsigned int nyp = pk[gr][ex][ey + 1][wz];
            unsigned int lo  = (wz > 0) ? pk[gr][ex][ey][wz - 1] : 0u;
            unsigned int hi  = (wz < 2) ? pk[gr][ex][ey][wz + 1] : 0u;
            unsigned int interior = w & nxm & nxp & nym & nyp
                                  & ((w << 1) | (lo >> 31))
                                  & ((w >> 1) | (hi << 31));
            bres = w & ~interior;
        }
        bd[gr][bx][by][wz] = bres;
    }
    __syncthreads();

    // ---- Phase C: dilation + counts on the owned 8x8x3 words.
    unsigned long long acc = 0ull;
    if (tid < TW * TW * 3) {
        int ox = tid / (TW * 3);
        int r  = tid % (TW * 3);
        int oy = r / 3;
        int wz = r % 3;
        int bx = ox + 1, by = oy + 1;
        unsigned int Bp = bd[0][bx][by][wz];
        unsigned int Bg = bd[1][bx][by][wz];

        unsigned int gzm = (wz > 0) ? bd[1][bx][by][wz - 1] : 0u;
        unsigned int gzp = (wz < 2) ? bd[1][bx][by][wz + 1] : 0u;
        unsigned int dg = Bg | (Bg << 1) | (Bg >> 1) | (gzm >> 31) | (gzp << 31)
                        | bd[1][bx - 1][by][wz] | bd[1][bx + 1][by][wz]
                        | bd[1][bx][by - 1][wz] | bd[1][bx][by + 1][wz];

        unsigned int pzm = (wz > 0) ? bd[0][bx][by][wz - 1] : 0u;
        unsigned int pzp = (wz < 2) ? bd[0][bx][by][wz + 1] : 0u;
        unsigned int dp = Bp | (Bp << 1) | (Bp >> 1) | (pzm >> 31) | (pzp << 31)
                        | bd[0][bx - 1][by][wz] | bd[0][bx + 1][by][wz]
                        | bd[0][bx][by - 1][wz] | bd[0][bx][by + 1][wz];

        unsigned int novp = __popc(Bp & dg);
        unsigned int novg = __popc(Bg & dp);
        unsigned int nbp  = __popc(Bp);
        unsigned int nbg  = __popc(Bg);
        // fields [0:16)=ovp [16:32)=ovg [32:48)=bp [48:64)=bg;
        // block sum <= 192*32 = 6144 < 65536: no cross-field carry.
        acc = (unsigned long long)novp
            + ((unsigned long long)novg << 16)
            + ((unsigned long long)nbp  << 32)
            + ((unsigned long long)nbg  << 48);
    }
    #pragma unroll
    for (int off = 32; off >= 1; off >>= 1)
        acc += __shfl_down(acc, off, 64);
    if (lane == 0) wsum[wid] = acc;
    __syncthreads();

    const int bid = blockIdx.y * NBX + blockIdx.x;
    if (tid == 0) {
        unsigned long long t = 0ull;
        #pragma unroll
        for (int w = 0; w < 8; ++w) t += wsum[w];
        uint4 rr;
        rr.x = (unsigned int)( t        & 0xFFFF);
        rr.y = (unsigned int)((t >> 16) & 0xFFFF);
        rr.z = (unsigned int)((t >> 32) & 0xFFFF);
        rr.w = (unsigned int)((t >> 48) & 0xFFFF);
        partials[bid] = rr;
        __threadfence();   // make partial visible before the flag
        __hip_atomic_store(&flags[bid * FLAG_STRIDE], FLAG_SET,
                           __ATOMIC_RELEASE, __HIP_MEMORY_SCOPE_AGENT);
    }

    if (bid != 0) return;

    // ---- Block (0,0): wait for all partials, reduce, write the scalar.
    // Stale-SET flags from a previous graph replay are benign: every block's
    // partial is a pure function of the (unchanged) inputs, so any old/new
    // byte mix read here is bit-identical to this replay's values.
    if (tid < NBLKS) {
        while (__hip_atomic_load(&flags[tid * FLAG_STRIDE],
                                 __ATOMIC_ACQUIRE, __HIP_MEMORY_SCOPE_AGENT)
               != FLAG_SET) {
            __builtin_amdgcn_s_sleep(2);
        }
    }
    __syncthreads();

    if (tid < NBLKS) {
        uint4 v = partials[tid];
        s[0][tid] = v.x; s[1][tid] = v.y; s[2][tid] = v.z; s[3][tid] = v.w;
    }
    __syncthreads();
    for (int off = 128; off >= 1; off >>= 1) {
        if (tid < off) {
            s[0][tid] += s[0][tid + off];
            s[1][tid] += s[1][tid + off];
            s[2][tid] += s[2][tid + off];
            s[3][tid] += s[3][tid + off];
        }
        __syncthreads();
    }
    if (tid == 0) {
        float num   = (float)(s[0][0] + s[1][0]);
        float denom = (float)(s[2][0] + s[3][0]);
        out[0] = denom > 0.0f ? num / denom : 0.0f;
    }
}

extern "C" void kernel_launch(void* const* d_in, const int* in_sizes, int n_in,
                              void* d_out, int out_size, void* d_ws, size_t ws_size,
                              hipStream_t stream) {
    const float* net = (const float*)d_in[0];
    const int*   tgt = (const int*)d_in[1];
    float* out = (float*)d_out;

    uint4*        partials = (uint4*)d_ws;                          // 4 KiB
    unsigned int* flags    = (unsigned int*)((char*)d_ws + 4096);   // 16 KiB (64 B/flag)

    fused_kernel<<<dim3(NBX, NBY), 512, 0, stream>>>(net, tgt, partials, flags, out);
}

// Round 6
// 18.204 us; speedup vs baseline: 1.2904x; 1.2904x over previous
//
#include <hip/hip_runtime.h>

#define D0 128
#define D1 128
#define D2 96
#define TW 8                 // owned tile width in x and y
#define EXT 12               // TW + 2*2 halo (dil needs bnd+-1, bnd needs occ+-2)
#define BND 10               // EXT - 2 (region where boundary words are valid)
#define NBX (D0 / TW)        // 16
#define NBY (D1 / TW)        // 16
#define NBLKS (NBX * NBY)    // 256 partials

// ---------------------------------------------------------------------------
// Fused: pack -> boundary -> 7-point dilation (d2<=1 test) -> per-block counts.
// One block per 8x8 column tile; halo recomputed, no inter-block communication.
// (Single-dispatch flag-handshake variant measured WORSE: cross-XCD
//  release/acquire + threadfence cost ~5.8 us vs ~1.3 us dispatch overhead.)
// ---------------------------------------------------------------------------
__global__ __launch_bounds__(512) void fused_kernel(const float* __restrict__ net,
                                                    const int* __restrict__ tgt,
                                                    uint4* __restrict__ partials) {
    __shared__ unsigned int pk[2][EXT][EXT][3];   // packed occupancy (p,g)
    __shared__ unsigned int bd[2][BND][BND][3];   // boundary words (p,g)
    __shared__ unsigned long long wsum[8];

    const int tid  = threadIdx.x;
    const int lane = tid & 63;
    const int wid  = tid >> 6;                    // 8 waves
    const int x0   = blockIdx.x * TW;
    const int y0   = blockIdx.y * TW;

    // ---- Phase A: pack 12x12 ext columns (96 z -> 3 words) via ballot.
    // Wave w owns ext-columns [w*18, w*18+18); batch 6 columns so 24 global
    // loads are in flight per wave before the first ballot consumes them
    // (1 block/CU -> no TLP; ILP must hide load latency).
    for (int c0 = wid * 18; c0 < wid * 18 + 18; c0 += 6) {
        bool pl[6], gl[6], ph[6], gh[6];
        #pragma unroll
        for (int j = 0; j < 6; ++j) {
            int c  = c0 + j;
            int ex = c / EXT, ey = c % EXT;
            int cx = x0 - 2 + ex, cy = y0 - 2 + ey;
            bool in = (cx >= 0 && cx < D0 && cy >= 0 && cy < D1);
            long base = in ? ((long)(cx * D1 + cy)) * D2 : 0;
            bool in2 = in && (lane < 32);
            pl[j] = in  ? (net[base + lane] > 0.0f)      : false;  // z in [0,64)
            gl[j] = in  ? (tgt[base + lane] != 0)        : false;
            ph[j] = in2 ? (net[base + 64 + lane] > 0.0f) : false;  // z in [64,96)
            gh[j] = in2 ? (tgt[base + 64 + lane] != 0)   : false;
        }
        #pragma unroll
        for (int j = 0; j < 6; ++j) {
            unsigned long long mp  = __ballot(pl[j]);
            unsigned long long mg  = __ballot(gl[j]);
            unsigned long long mp2 = __ballot(ph[j]);
            unsigned long long mg2 = __ballot(gh[j]);
            if (lane == 0) {
                int c  = c0 + j;
                int ex = c / EXT, ey = c % EXT;
                pk[0][ex][ey][0] = (unsigned int)mp;
                pk[0][ex][ey][1] = (unsigned int)(mp >> 32);
                pk[0][ex][ey][2] = (unsigned int)mp2;
                pk[1][ex][ey][0] = (unsigned int)mg;
                pk[1][ex][ey][1] = (unsigned int)(mg >> 32);
                pk[1][ex][ey][2] = (unsigned int)mg2;
            }
        }
    }
    __syncthreads();

    // ---- Phase B: boundary words on the 10x10 ext-1 region (both grids).
    // boundary = fg & ~(all 6 neighbors fg); out-of-volume = background
    // (pk==0 outside the volume; z shifts inject 0 at the ends).
    for (int it = tid; it < 2 * BND * BND * 3; it += 512) {
        int gr = it / (BND * BND * 3);
        int r  = it % (BND * BND * 3);
        int bx = r / (BND * 3);
        int r2 = r % (BND * 3);
        int by = r2 / 3;
        int wz = r2 % 3;
        int ex = bx + 1, ey = by + 1;
        unsigned int w = pk[gr][ex][ey][wz];
        unsigned int bres = 0u;
        if (w) {
            unsigned int nxm = pk[gr][ex - 1][ey][wz];
            unsigned int nxp = pk[gr][ex + 1][ey][wz];
            unsigned int nym = pk[gr][ex][ey - 1][wz];
            unsigned int nyp = pk[gr][ex][ey + 1][wz];
            unsigned int lo  = (wz > 0) ? pk[gr][ex][ey][wz - 1] : 0u;
            unsigned int hi  = (wz < 2) ? pk[gr][ex][ey][wz + 1] : 0u;
            unsigned int interior = w & nxm & nxp & nym & nyp
                                  & ((w << 1) | (lo >> 31))
                                  & ((w >> 1) | (hi << 31));
            bres = w & ~interior;
        }
        bd[gr][bx][by][wz] = bres;
    }
    __syncthreads();

    // ---- Phase C: dilation + counts on the owned 8x8x3 words.
    unsigned long long acc = 0ull;
    if (tid < TW * TW * 3) {
        int ox = tid / (TW * 3);
        int r  = tid % (TW * 3);
        int oy = r / 3;
        int wz = r % 3;
        int bx = ox + 1, by = oy + 1;
        unsigned int Bp = bd[0][bx][by][wz];
        unsigned int Bg = bd[1][bx][by][wz];

        unsigned int gzm = (wz > 0) ? bd[1][bx][by][wz - 1] : 0u;
        unsigned int gzp = (wz < 2) ? bd[1][bx][by][wz + 1] : 0u;
        unsigned int dg = Bg | (Bg << 1) | (Bg >> 1) | (gzm >> 31) | (gzp << 31)
                        | bd[1][bx - 1][by][wz] | bd[1][bx + 1][by][wz]
                        | bd[1][bx][by - 1][wz] | bd[1][bx][by + 1][wz];

        unsigned int pzm = (wz > 0) ? bd[0][bx][by][wz - 1] : 0u;
        unsigned int pzp = (wz < 2) ? bd[0][bx][by][wz + 1] : 0u;
        unsigned int dp = Bp | (Bp << 1) | (Bp >> 1) | (pzm >> 31) | (pzp << 31)
                        | bd[0][bx - 1][by][wz] | bd[0][bx + 1][by][wz]
                        | bd[0][bx][by - 1][wz] | bd[0][bx][by + 1][wz];

        unsigned int novp = __popc(Bp & dg);
        unsigned int novg = __popc(Bg & dp);
        unsigned int nbp  = __popc(Bp);
        unsigned int nbg  = __popc(Bg);
        // fields [0:16)=ovp [16:32)=ovg [32:48)=bp [48:64)=bg;
        // block sum <= 192*32 = 6144 < 65536: no cross-field carry.
        acc = (unsigned long long)novp
            + ((unsigned long long)novg << 16)
            + ((unsigned long long)nbp  << 32)
            + ((unsigned long long)nbg  << 48);
    }
    #pragma unroll
    for (int off = 32; off >= 1; off >>= 1)
        acc += __shfl_down(acc, off, 64);
    if (lane == 0) wsum[wid] = acc;
    __syncthreads();
    if (tid == 0) {
        unsigned long long t = 0ull;
        #pragma unroll
        for (int w = 0; w < 8; ++w) t += wsum[w];
        uint4 rr;
        rr.x = (unsigned int)( t        & 0xFFFF);
        rr.y = (unsigned int)((t >> 16) & 0xFFFF);
        rr.z = (unsigned int)((t >> 32) & 0xFFFF);
        rr.w = (unsigned int)((t >> 48) & 0xFFFF);
        partials[blockIdx.y * NBX + blockIdx.x] = rr;
    }
}

// ---------------------------------------------------------------------------
// Finalize: one wave; lane L sums partials[L], L+64, L+128, L+192 per field,
// then 6-step shuffle reduce per field. No LDS, no extra barriers.
// ---------------------------------------------------------------------------
__global__ void finalize_kernel(const uint4* __restrict__ partials,
                                float* __restrict__ out) {
    int lane = threadIdx.x;   // 64 threads
    unsigned int ovp = 0, ovg = 0, bp = 0, bg = 0;
    #pragma unroll
    for (int k = 0; k < NBLKS / 64; ++k) {
        uint4 v = partials[k * 64 + lane];
        ovp += v.x; ovg += v.y; bp += v.z; bg += v.w;
    }
    #pragma unroll
    for (int off = 32; off >= 1; off >>= 1) {
        ovp += __shfl_down(ovp, off, 64);
        ovg += __shfl_down(ovg, off, 64);
        bp  += __shfl_down(bp,  off, 64);
        bg  += __shfl_down(bg,  off, 64);
    }
    if (lane == 0) {
        float num   = (float)(ovp + ovg);
        float denom = (float)(bp + bg);
        out[0] = denom > 0.0f ? num / denom : 0.0f;
    }
}

extern "C" void kernel_launch(void* const* d_in, const int* in_sizes, int n_in,
                              void* d_out, int out_size, void* d_ws, size_t ws_size,
                              hipStream_t stream) {
    const float* net = (const float*)d_in[0];
    const int*   tgt = (const int*)d_in[1];
    float* out = (float*)d_out;
    uint4* partials = (uint4*)d_ws;   // 256 * 16 B

    fused_kernel<<<dim3(NBX, NBY), 512, 0, stream>>>(net, tgt, partials);
    finalize_kernel<<<1, 64, 0, stream>>>(partials, out);
}

// Round 7
// 13.438 us; speedup vs baseline: 1.7481x; 1.3547x over previous
//
#include <hip/hip_runtime.h>

#define D0 128
#define D1 128
#define D2 96
#define TW 8                 // owned tile width in x and y
#define EXT 12               // TW + 2*2 halo (dil needs bnd+-1, bnd needs occ+-2)
#define BND 10               // EXT - 2 (region where boundary words are valid)
#define NBX (D0 / TW)        // 16
#define NBY (D1 / TW)        // 16
#define NBLKS (NBX * NBY)    // 256 partials
#define NELEM (EXT * EXT * 24)        // float4-chunks per array = 3456
#define NF (2 * NELEM)                // total chunks (net + tgt) = 6912

// ---------------------------------------------------------------------------
// Fused: vectorized pack -> boundary -> 7-point dilation (d2<=1) -> counts.
// One block per 8x8 column tile; halo recomputed, no inter-block comm.
// (Single-dispatch flag-handshake variant measured WORSE (R5): cross-XCD
//  release/acquire + threadfence cost ~5.8 us vs ~1.3 us dispatch overhead.)
// ---------------------------------------------------------------------------
__global__ __launch_bounds__(512) void fused_kernel(const float* __restrict__ net,
                                                    const int* __restrict__ tgt,
                                                    uint4* __restrict__ partials) {
    __shared__ unsigned int pk[2][EXT][EXT][3];   // packed occupancy (p,g)
    __shared__ unsigned int bd[2][BND][BND][3];   // boundary words (p,g)
    __shared__ unsigned long long wsum[8];

    unsigned int* pkf = &pk[0][0][0][0];          // flat view: 864 words

    const int tid  = threadIdx.x;
    const int lane = tid & 63;
    const int wid  = tid >> 6;                    // 8 waves
    const int x0   = blockIdx.x * TW;
    const int y0   = blockIdx.y * TW;

    // ---- Phase A (vectorized): flat f over [0, NF).
    // arr = f/NELEM (0=net, 1=tgt); r = f%NELEM; col = r/24; k = r%24; z4 = 4k.
    // Lane loads float4/int4 (coalesced, 16 B/lane), makes a 4-bit nibble at
    // bit offset (tid&7)*4, OR-folds across its aligned 8-lane group (3
    // shfl_xor), and lane tid%8==0 writes the finished word pkf[f>>3].
    // Identities: 24%8==0 so every aligned 8-lane group covers exactly one
    // (array, column, word); NELEM%64==0 so `arr` is wave-uniform; words are
    // each written exactly once (NF/8 == 864 == total pk words).
    const int off = (tid & 7) * 4;
    #pragma unroll
    for (int round = 0; round < (NF + 511) / 512; ++round) {
        int f = round * 512 + tid;
        unsigned int nib = 0u;
        if (f < NF) {
            int arr = (f >= NELEM) ? 1 : 0;
            int r   = f - arr * NELEM;
            int col = r / 24;
            int k   = r % 24;
            int cx  = x0 - 2 + col / EXT;
            int cy  = y0 - 2 + col % EXT;
            if (cx >= 0 && cx < D0 && cy >= 0 && cy < D1) {
                long eb = ((long)(cx * D1 + cy)) * D2 + k * 4;
                if (arr == 0) {
                    float4 v = *(const float4*)(net + eb);
                    nib = (v.x > 0.0f ? 1u : 0u) | (v.y > 0.0f ? 2u : 0u)
                        | (v.z > 0.0f ? 4u : 0u) | (v.w > 0.0f ? 8u : 0u);
                } else {
                    int4 v = *(const int4*)(tgt + eb);
                    nib = (v.x ? 1u : 0u) | (v.y ? 2u : 0u)
                        | (v.z ? 4u : 0u) | (v.w ? 8u : 0u);
                }
            }
        }
        unsigned int w = nib << off;
        w |= __shfl_xor(w, 1, 64);
        w |= __shfl_xor(w, 2, 64);
        w |= __shfl_xor(w, 4, 64);
        if ((tid & 7) == 0 && f < NF) pkf[f >> 3] = w;
    }
    __syncthreads();

    // ---- Phase B: boundary words on the 10x10 ext-1 region (both grids).
    // boundary = fg & ~(all 6 neighbors fg); out-of-volume = background
    // (pk==0 outside the volume; z shifts inject 0 at the ends).
    for (int it = tid; it < 2 * BND * BND * 3; it += 512) {
        int gr = it / (BND * BND * 3);
        int r  = it % (BND * BND * 3);
        int bx = r / (BND * 3);
        int r2 = r % (BND * 3);
        int by = r2 / 3;
        int wz = r2 % 3;
        int ex = bx + 1, ey = by + 1;
        unsigned int w = pk[gr][ex][ey][wz];
        unsigned int bres = 0u;
        if (w) {
            unsigned int nxm = pk[gr][ex - 1][ey][wz];
            unsigned int nxp = pk[gr][ex + 1][ey][wz];
            unsigned int nym = pk[gr][ex][ey - 1][wz];
            unsigned int nyp = pk[gr][ex][ey + 1][wz];
            unsigned int lo  = (wz > 0) ? pk[gr][ex][ey][wz - 1] : 0u;
            unsigned int hi  = (wz < 2) ? pk[gr][ex][ey][wz + 1] : 0u;
            unsigned int interior = w & nxm & nxp & nym & nyp
                                  & ((w << 1) | (lo >> 31))
                                  & ((w >> 1) | (hi << 31));
            bres = w & ~interior;
        }
        bd[gr][bx][by][wz] = bres;
    }
    __syncthreads();

    // ---- Phase C: dilation + counts on the owned 8x8x3 words.
    unsigned long long acc = 0ull;
    if (tid < TW * TW * 3) {
        int ox = tid / (TW * 3);
        int r  = tid % (TW * 3);
        int oy = r / 3;
        int wz = r % 3;
        int bx = ox + 1, by = oy + 1;
        unsigned int Bp = bd[0][bx][by][wz];
        unsigned int Bg = bd[1][bx][by][wz];

        unsigned int gzm = (wz > 0) ? bd[1][bx][by][wz - 1] : 0u;
        unsigned int gzp = (wz < 2) ? bd[1][bx][by][wz + 1] : 0u;
        unsigned int dg = Bg | (Bg << 1) | (Bg >> 1) | (gzm >> 31) | (gzp << 31)
                        | bd[1][bx - 1][by][wz] | bd[1][bx + 1][by][wz]
                        | bd[1][bx][by - 1][wz] | bd[1][bx][by + 1][wz];

        unsigned int pzm = (wz > 0) ? bd[0][bx][by][wz - 1] : 0u;
        unsigned int pzp = (wz < 2) ? bd[0][bx][by][wz + 1] : 0u;
        unsigned int dp = Bp | (Bp << 1) | (Bp >> 1) | (pzm >> 31) | (pzp << 31)
                        | bd[0][bx - 1][by][wz] | bd[0][bx + 1][by][wz]
                        | bd[0][bx][by - 1][wz] | bd[0][bx][by + 1][wz];

        unsigned int novp = __popc(Bp & dg);
        unsigned int novg = __popc(Bg & dp);
        unsigned int nbp  = __popc(Bp);
        unsigned int nbg  = __popc(Bg);
        // fields [0:16)=ovp [16:32)=ovg [32:48)=bp [48:64)=bg;
        // block sum <= 192*32 = 6144 < 65536: no cross-field carry.
        acc = (unsigned long long)novp
            + ((unsigned long long)novg << 16)
            + ((unsigned long long)nbp  << 32)
            + ((unsigned long long)nbg  << 48);
    }
    #pragma unroll
    for (int offr = 32; offr >= 1; offr >>= 1)
        acc += __shfl_down(acc, offr, 64);
    if (lane == 0) wsum[wid] = acc;
    __syncthreads();
    if (tid == 0) {
        unsigned long long t = 0ull;
        #pragma unroll
        for (int w = 0; w < 8; ++w) t += wsum[w];
        uint4 rr;
        rr.x = (unsigned int)( t        & 0xFFFF);
        rr.y = (unsigned int)((t >> 16) & 0xFFFF);
        rr.z = (unsigned int)((t >> 32) & 0xFFFF);
        rr.w = (unsigned int)((t >> 48) & 0xFFFF);
        partials[blockIdx.y * NBX + blockIdx.x] = rr;
    }
}

// ---------------------------------------------------------------------------
// Finalize: one wave; lane L sums partials[L], L+64, L+128, L+192 per field,
// then 6-step shuffle reduce per field. No LDS, no extra barriers.
// ---------------------------------------------------------------------------
__global__ void finalize_kernel(const uint4* __restrict__ partials,
                                float* __restrict__ out) {
    int lane = threadIdx.x;   // 64 threads
    unsigned int ovp = 0, ovg = 0, bp = 0, bg = 0;
    #pragma unroll
    for (int k = 0; k < NBLKS / 64; ++k) {
        uint4 v = partials[k * 64 + lane];
        ovp += v.x; ovg += v.y; bp += v.z; bg += v.w;
    }
    #pragma unroll
    for (int off = 32; off >= 1; off >>= 1) {
        ovp += __shfl_down(ovp, off, 64);
        ovg += __shfl_down(ovg, off, 64);
        bp  += __shfl_down(bp,  off, 64);
        bg  += __shfl_down(bg,  off, 64);
    }
    if (lane == 0) {
        float num   = (float)(ovp + ovg);
        float denom = (float)(bp + bg);
        out[0] = denom > 0.0f ? num / denom : 0.0f;
    }
}

extern "C" void kernel_launch(void* const* d_in, const int* in_sizes, int n_in,
                              void* d_out, int out_size, void* d_ws, size_t ws_size,
                              hipStream_t stream) {
    const float* net = (const float*)d_in[0];
    const int*   tgt = (const int*)d_in[1];
    float* out = (float*)d_out;
    uint4* partials = (uint4*)d_ws;   // 256 * 16 B

    fused_kernel<<<dim3(NBX, NBY), 512, 0, stream>>>(net, tgt, partials);
    finalize_kernel<<<1, 64, 0, stream>>>(partials, out);
}

// Round 8
// 12.310 us; speedup vs baseline: 1.9082x; 1.0916x over previous
//
#include <hip/hip_runtime.h>

#define D0 128
#define D1 128
#define D2 96
#define TW 8                 // owned tile width in x and y
#define EXT 12               // TW + 2*2 halo (dil needs bnd+-1, bnd needs occ+-2)
#define BND 10               // EXT - 2 (region where boundary words are valid)
#define NBX (D0 / TW)        // 16
#define NBY (D1 / TW)        // 16
#define NBLKS (NBX * NBY)    // 256 partials
#define NPKW (2 * EXT * EXT * 3)      // total packed words (both arrays) = 864

// ---------------------------------------------------------------------------
// Fused: word-per-thread pack -> boundary -> 7-point dilation (d2<=1) -> counts.
// One block per 8x8 column tile; halo recomputed, no inter-block comm.
// (Single-dispatch flag-handshake variant measured WORSE (R5): cross-XCD
//  release/acquire + threadfence cost ~5.8 us vs ~1.3 us dispatch overhead.)
// ---------------------------------------------------------------------------
__global__ __launch_bounds__(512) void fused_kernel(const float* __restrict__ net,
                                                    const int* __restrict__ tgt,
                                                    uint4* __restrict__ partials) {
    __shared__ unsigned int pk[2][EXT][EXT][3];   // packed occupancy (p,g)
    __shared__ unsigned int bd[2][BND][BND][3];   // boundary words (p,g)
    __shared__ unsigned long long wsum[8];

    unsigned int* pkf = &pk[0][0][0][0];          // flat view: NPKW words

    const int tid  = threadIdx.x;
    const int lane = tid & 63;
    const int wid  = tid >> 6;                    // 8 waves
    const int x0   = blockIdx.x * TW;
    const int y0   = blockIdx.y * TW;

    // ---- Phase A: one thread builds one packed word (32 z-voxels = 128 B).
    // f = gr*432 + col*3 + wz  (matches pk's flat layout exactly).
    // 8 independent dwordx4 loads per thread (ILP), 32 compares, 1 ds_write.
    // No shuffles, no ballots; every word written exactly once.
    #pragma unroll
    for (int round = 0; round < 2; ++round) {
        int f = round * 512 + tid;
        if (f < NPKW) {
            int gr  = (f >= NPKW / 2) ? 1 : 0;
            int r   = f - gr * (NPKW / 2);
            int col = r / 3;
            int wz  = r - col * 3;
            int cx  = x0 - 2 + col / EXT;
            int cy  = y0 - 2 + col % EXT;
            unsigned int w = 0u;
            if (cx >= 0 && cx < D0 && cy >= 0 && cy < D1) {
                long eb = ((long)(cx * D1 + cy)) * D2 + wz * 32;
                if (gr == 0) {
                    const float4* s = (const float4*)(net + eb);
                    float4 v[8];
                    #pragma unroll
                    for (int j = 0; j < 8; ++j) v[j] = s[j];
                    #pragma unroll
                    for (int j = 0; j < 8; ++j) {
                        w |= (v[j].x > 0.0f ? 1u : 0u) << (j * 4);
                        w |= (v[j].y > 0.0f ? 2u : 0u) << (j * 4);
                        w |= (v[j].z > 0.0f ? 4u : 0u) << (j * 4);
                        w |= (v[j].w > 0.0f ? 8u : 0u) << (j * 4);
                    }
                } else {
                    const int4* s = (const int4*)(tgt + eb);
                    int4 v[8];
                    #pragma unroll
                    for (int j = 0; j < 8; ++j) v[j] = s[j];
                    #pragma unroll
                    for (int j = 0; j < 8; ++j) {
                        w |= (v[j].x ? 1u : 0u) << (j * 4);
                        w |= (v[j].y ? 2u : 0u) << (j * 4);
                        w |= (v[j].z ? 4u : 0u) << (j * 4);
                        w |= (v[j].w ? 8u : 0u) << (j * 4);
                    }
                }
            }
            pkf[f] = w;
        }
    }
    __syncthreads();

    // ---- Phase B: boundary words on the 10x10 ext-1 region (both grids).
    // boundary = fg & ~(all 6 neighbors fg); out-of-volume = background
    // (pk==0 outside the volume; z shifts inject 0 at the ends).
    for (int it = tid; it < 2 * BND * BND * 3; it += 512) {
        int gr = it / (BND * BND * 3);
        int r  = it % (BND * BND * 3);
        int bx = r / (BND * 3);
        int r2 = r % (BND * 3);
        int by = r2 / 3;
        int wz = r2 % 3;
        int ex = bx + 1, ey = by + 1;
        unsigned int w = pk[gr][ex][ey][wz];
        unsigned int bres = 0u;
        if (w) {
            unsigned int nxm = pk[gr][ex - 1][ey][wz];
            unsigned int nxp = pk[gr][ex + 1][ey][wz];
            unsigned int nym = pk[gr][ex][ey - 1][wz];
            unsigned int nyp = pk[gr][ex][ey + 1][wz];
            unsigned int lo  = (wz > 0) ? pk[gr][ex][ey][wz - 1] : 0u;
            unsigned int hi  = (wz < 2) ? pk[gr][ex][ey][wz + 1] : 0u;
            unsigned int interior = w & nxm & nxp & nym & nyp
                                  & ((w << 1) | (lo >> 31))
                                  & ((w >> 1) | (hi << 31));
            bres = w & ~interior;
        }
        bd[gr][bx][by][wz] = bres;
    }
    __syncthreads();

    // ---- Phase C: dilation + counts on the owned 8x8x3 words.
    unsigned long long acc = 0ull;
    if (tid < TW * TW * 3) {
        int ox = tid / (TW * 3);
        int r  = tid % (TW * 3);
        int oy = r / 3;
        int wz = r % 3;
        int bx = ox + 1, by = oy + 1;
        unsigned int Bp = bd[0][bx][by][wz];
        unsigned int Bg = bd[1][bx][by][wz];

        unsigned int gzm = (wz > 0) ? bd[1][bx][by][wz - 1] : 0u;
        unsigned int gzp = (wz < 2) ? bd[1][bx][by][wz + 1] : 0u;
        unsigned int dg = Bg | (Bg << 1) | (Bg >> 1) | (gzm >> 31) | (gzp << 31)
                        | bd[1][bx - 1][by][wz] | bd[1][bx + 1][by][wz]
                        | bd[1][bx][by - 1][wz] | bd[1][bx][by + 1][wz];

        unsigned int pzm = (wz > 0) ? bd[0][bx][by][wz - 1] : 0u;
        unsigned int pzp = (wz < 2) ? bd[0][bx][by][wz + 1] : 0u;
        unsigned int dp = Bp | (Bp << 1) | (Bp >> 1) | (pzm >> 31) | (pzp << 31)
                        | bd[0][bx - 1][by][wz] | bd[0][bx + 1][by][wz]
                        | bd[0][bx][by - 1][wz] | bd[0][bx][by + 1][wz];

        unsigned int novp = __popc(Bp & dg);
        unsigned int novg = __popc(Bg & dp);
        unsigned int nbp  = __popc(Bp);
        unsigned int nbg  = __popc(Bg);
        // fields [0:16)=ovp [16:32)=ovg [32:48)=bp [48:64)=bg;
        // block sum <= 192*32 = 6144 < 65536: no cross-field carry.
        acc = (unsigned long long)novp
            + ((unsigned long long)novg << 16)
            + ((unsigned long long)nbp  << 32)
            + ((unsigned long long)nbg  << 48);
    }
    #pragma unroll
    for (int offr = 32; offr >= 1; offr >>= 1)
        acc += __shfl_down(acc, offr, 64);
    if (lane == 0) wsum[wid] = acc;
    __syncthreads();
    if (tid == 0) {
        unsigned long long t = 0ull;
        #pragma unroll
        for (int w = 0; w < 8; ++w) t += wsum[w];
        uint4 rr;
        rr.x = (unsigned int)( t        & 0xFFFF);
        rr.y = (unsigned int)((t >> 16) & 0xFFFF);
        rr.z = (unsigned int)((t >> 32) & 0xFFFF);
        rr.w = (unsigned int)((t >> 48) & 0xFFFF);
        partials[blockIdx.y * NBX + blockIdx.x] = rr;
    }
}

// ---------------------------------------------------------------------------
// Finalize: one wave; lane L sums partials[L], L+64, L+128, L+192 per field,
// then 6-step shuffle reduce per field. No LDS, no extra barriers.
// ---------------------------------------------------------------------------
__global__ void finalize_kernel(const uint4* __restrict__ partials,
                                float* __restrict__ out) {
    int lane = threadIdx.x;   // 64 threads
    unsigned int ovp = 0, ovg = 0, bp = 0, bg = 0;
    #pragma unroll
    for (int k = 0; k < NBLKS / 64; ++k) {
        uint4 v = partials[k * 64 + lane];
        ovp += v.x; ovg += v.y; bp += v.z; bg += v.w;
    }
    #pragma unroll
    for (int off = 32; off >= 1; off >>= 1) {
        ovp += __shfl_down(ovp, off, 64);
        ovg += __shfl_down(ovg, off, 64);
        bp  += __shfl_down(bp,  off, 64);
        bg  += __shfl_down(bg,  off, 64);
    }
    if (lane == 0) {
        float num   = (float)(ovp + ovg);
        float denom = (float)(bp + bg);
        out[0] = denom > 0.0f ? num / denom : 0.0f;
    }
}

extern "C" void kernel_launch(void* const* d_in, const int* in_sizes, int n_in,
                              void* d_out, int out_size, void* d_ws, size_t ws_size,
                              hipStream_t stream) {
    const float* net = (const float*)d_in[0];
    const int*   tgt = (const int*)d_in[1];
    float* out = (float*)d_out;
    uint4* partials = (uint4*)d_ws;   // 256 * 16 B

    fused_kernel<<<dim3(NBX, NBY), 512, 0, stream>>>(net, tgt, partials);
    finalize_kernel<<<1, 64, 0, stream>>>(partials, out);
}